// Round 7
// baseline (430.468 us; speedup 1.0000x reference)
//
#include <hip/hip_runtime.h>
#include <hip/hip_bf16.h>
#include <stdint.h>

typedef __attribute__((ext_vector_type(8))) short short8;
typedef __attribute__((ext_vector_type(4))) float f32x4;

#define S_LEN   4096
#define HID_DIM 2048
#define NHEAD   16
#define NKV     4
#define DHEAD   128
#define QPG     4
#define GROUP   768   // (QPG+2)*DHEAD
#define TOTAL   3072  // NKV*GROUP

__device__ __forceinline__ ushort f2bf(float f) {
    union { float f; uint32_t u; } c; c.f = f;
    uint32_t u = c.u;
    u += 0x7fff + ((u >> 16) & 1);   // RNE
    return (ushort)(u >> 16);
}

__device__ __forceinline__ void gld_lds16(const void* g, void* l) {
    __builtin_amdgcn_global_load_lds(
        (const __attribute__((address_space(1))) void*)g,
        (__attribute__((address_space(3))) void*)l, 16, 0, 0);
}

// ---------------------------------------------------------------------------
// fp32 -> bf16 convert. mode 1: scale q-head rows of wqkv by 1/sqrt(D)
// ---------------------------------------------------------------------------
__global__ __launch_bounds__(256)
void cvt_f32_bf16(const float* __restrict__ src, ushort* __restrict__ dst,
                  int n4, int mode)
{
    int i = blockIdx.x * blockDim.x + threadIdx.x;
    int stride = gridDim.x * blockDim.x;
    for (; i < n4; i += stride) {
        float sc = 1.0f;
        if (mode == 1) {
            int row = i >> 9;                      // (i*4)/2048
            sc = ((row % GROUP) < QPG * DHEAD) ? 0.088388347648318447f : 1.0f;
        }
        float4 v = ((const float4*)src)[i];
        ushort4 o;
        o.x = f2bf(v.x * sc); o.y = f2bf(v.y * sc);
        o.z = f2bf(v.z * sc); o.w = f2bf(v.w * sc);
        ((ushort4*)dst)[i] = o;
    }
}

__global__ __launch_bounds__(256)
void zero_f4(float4* __restrict__ p, int n4)
{
    int i = blockIdx.x * blockDim.x + threadIdx.x;
    int stride = gridDim.x * blockDim.x;
    float4 z = {0.f, 0.f, 0.f, 0.f};
    for (; i < n4; i += stride) p[i] = z;
}

// ---------------------------------------------------------------------------
// C[M,N] = A[M,K] * B[N,K]^T (bf16 in, fp32 accum). m97-style staging.
// WRITE_VT: V column-blocks store transposed to VT only (qkv store skipped).
// ---------------------------------------------------------------------------
__device__ __forceinline__ void store_c(ushort* C, size_t idx, float v) { C[idx] = f2bf(v); }
__device__ __forceinline__ void store_c(float*  C, size_t idx, float v) { C[idx] = v; }

template <typename OutT, bool WRITE_VT>
__global__ __launch_bounds__(256, 2)
void gemm_bt(const ushort* __restrict__ A, const ushort* __restrict__ B,
             OutT* __restrict__ C, ushort* __restrict__ VT,
             int M, int N, int K)
{
    __shared__ alignas(16) ushort Asl[128 * 32];
    __shared__ alignas(16) ushort Bsl[128 * 32];

    const int tid  = threadIdx.x;
    const int wave = tid >> 6;
    const int lane = tid & 63;
    const int quad = lane >> 4;
    const int l15  = lane & 15;
    const int wr   = wave >> 1;
    const int wc   = wave & 1;
    const int m0   = blockIdx.y * 128;
    const int n0   = blockIdx.x * 128;

    f32x4 acc[4][4];
#pragma unroll
    for (int i = 0; i < 4; i++)
#pragma unroll
        for (int j = 0; j < 4; j++) acc[i][j] = (f32x4)0.0f;

    for (int kb = 0; kb < K; kb += 32) {
        __syncthreads();
#pragma unroll
        for (int r = 0; r < 2; r++) {
            int idx = tid + r * 256;
            int row = idx >> 2, c8 = idx & 3;
            char* la = (char*)Asl + (size_t)(wave * 64 + r * 256) * 16;
            char* lb = (char*)Bsl + (size_t)(wave * 64 + r * 256) * 16;
            gld_lds16(A + (size_t)(m0 + row) * K + kb + c8 * 8, la);
            gld_lds16(B + (size_t)(n0 + row) * K + kb + c8 * 8, lb);
        }
        __syncthreads();

        short8 af[4], bf[4];
#pragma unroll
        for (int i = 0; i < 4; i++)
            af[i] = *(const short8*)(&Asl[(wr * 64 + i * 16 + l15) * 32 + quad * 8]);
#pragma unroll
        for (int j = 0; j < 4; j++)
            bf[j] = *(const short8*)(&Bsl[(wc * 64 + j * 16 + l15) * 32 + quad * 8]);
#pragma unroll
        for (int i = 0; i < 4; i++)
#pragma unroll
            for (int j = 0; j < 4; j++)
                acc[i][j] = __builtin_amdgcn_mfma_f32_16x16x32_bf16(
                    af[i], bf[j], acc[i][j], 0, 0, 0);
    }

    const bool v_block = WRITE_VT && ((n0 >> 7) % 6 == 5);
    if (!v_block) {
#pragma unroll
        for (int i = 0; i < 4; i++)
#pragma unroll
            for (int j = 0; j < 4; j++)
#pragma unroll
                for (int r = 0; r < 4; r++) {
                    int row = m0 + wr * 64 + i * 16 + quad * 4 + r;
                    int col = n0 + wc * 64 + j * 16 + l15;
                    store_c(C, (size_t)row * N + col, acc[i][j][r]);
                }
    } else {
        int g = (n0 >> 7) / 6;
#pragma unroll
        for (int i = 0; i < 4; i++)
#pragma unroll
            for (int j = 0; j < 4; j++) {
                int d    = wc * 64 + j * 16 + l15;
                int row0 = m0 + wr * 64 + i * 16 + quad * 4;
                ushort4 pk;
                pk.x = f2bf(acc[i][j][0]); pk.y = f2bf(acc[i][j][1]);
                pk.z = f2bf(acc[i][j][2]); pk.w = f2bf(acc[i][j][3]);
                *(ushort4*)(VT + (size_t)(g * 128 + d) * S_LEN + row0) = pk;
            }
    }
}

// ---------------------------------------------------------------------------
// Causal GQA flash attention, exactly-balanced (split heavy strips, 33 units
// per block) with S^T = K*Q^T trick: P exits in [q][kv]-writable C-layout
// (b64 packed P writes), softmax l is per-lane scalar (no in-loop shfls).
// ---------------------------------------------------------------------------
__global__ __launch_bounds__(256, 2)
void flash_attn(const ushort* __restrict__ qkv, const ushort* __restrict__ VT,
                ushort* __restrict__ out, float* __restrict__ o_slot,
                float* __restrict__ l_slot)
{
    const int b    = blockIdx.x;
    const int head = b >> 5;
    const int pair = (b >> 1) & 15;
    const int half = b & 1;
    const int g    = head >> 2;
    const int qh   = head & 3;
    const int p_h  = 31 - pair;
    const int H    = 2 * p_h + 2;           // 34..64
    const int slot = head * 16 + pair;

    const int tid  = threadIdx.x;
    const int wave = tid >> 6;
    const int lane = tid & 63;
    const int quad = lane >> 4;
    const int l15  = lane & 15;

    __shared__ alignas(16) ushort Kl[64][136];    // [kv][d]
    __shared__ alignas(16) ushort Vt[128][72];    // [d][kv]
    __shared__ alignas(16) ushort Pl[4][32][66];  // per-wave P [q][kv], stride 66

    int seg_p[2], seg_t0[2], seg_t1[2], seg_part[2];
    int nseg;
    if (half == 0) {
        nseg = 1;
        seg_p[0] = p_h;  seg_t0[0] = 0;  seg_t1[0] = 33;           seg_part[0] = 1;
    } else {
        nseg = 2;
        seg_p[0] = p_h;  seg_t0[0] = 33; seg_t1[0] = H;            seg_part[0] = 1;
        seg_p[1] = pair; seg_t0[1] = 0;  seg_t1[1] = 2 * pair + 2; seg_part[1] = 0;
    }

    const int koff = g * GROUP + QPG * DHEAD;

    for (int s = 0; s < nseg; s++) {
        const int p  = seg_p[s];
        const int t0 = seg_t0[s];
        const int t1 = seg_t1[s];
        const int q0 = p * 128;
        const int base = q0 + wave * 32;     // wave's first q-row

        // Q fragments (B-operand layout): lane n=l15 -> q row, k-chunk quad*8
        short8 qf[2][4];
#pragma unroll
        for (int nq = 0; nq < 2; nq++) {
            int row = base + nq * 16 + l15;
            const ushort* qp = qkv + (size_t)row * TOTAL + g * GROUP + qh * DHEAD + quad * 8;
#pragma unroll
            for (int ks = 0; ks < 4; ks++)
                qf[nq][ks] = *(const short8*)(qp + ks * 32);
        }

        f32x4 o[2][8];
#pragma unroll
        for (int oq = 0; oq < 2; oq++)
#pragma unroll
            for (int df = 0; df < 8; df++) o[oq][df] = (f32x4)0.0f;
        float l_vec[2] = {0.0f, 0.0f};       // per-lane: q = base + nq*16 + l15

        // prefetch first tile of this segment
        float4 kpre[4], vpre[4];
#pragma unroll
        for (int r = 0; r < 4; r++) {
            int c = tid + r * 256;
            int kr = c >> 4, kc = c & 15;
            kpre[r] = *(const float4*)(qkv + (size_t)(t0 * 64 + kr) * TOTAL + koff + kc * 8);
            int vd = c >> 3, vc = c & 7;
            vpre[r] = *(const float4*)(VT + (size_t)(g * 128 + vd) * S_LEN + t0 * 64 + vc * 8);
        }

        for (int t = t0; t < t1; t++) {
            __syncthreads();
#pragma unroll
            for (int r = 0; r < 4; r++) {
                int c = tid + r * 256;
                int kr = c >> 4, kc = c & 15;
                *(float4*)(&Kl[kr][kc * 8]) = kpre[r];
                int vd = c >> 3, vc = c & 7;
                *(float4*)(&Vt[vd][vc * 8]) = vpre[r];
            }
            __syncthreads();

            if (t + 1 < t1) {
                const int j1 = (t + 1) * 64;
#pragma unroll
                for (int r = 0; r < 4; r++) {
                    int c = tid + r * 256;
                    int kr = c >> 4, kc = c & 15;
                    kpre[r] = *(const float4*)(qkv + (size_t)(j1 + kr) * TOTAL + koff + kc * 8);
                    int vd = c >> 3, vc = c & 7;
                    vpre[r] = *(const float4*)(VT + (size_t)(g * 128 + vd) * S_LEN + j1 + vc * 8);
                }
            }

            const int j0 = t * 64;
            // S^T = K * Q^T  (A=kf from LDS, B=qf from registers)
            // sacc[mk][nq] C-layout: col=l15 -> q_local = nq*16+l15,
            //                        row=quad*4+r -> kv_local = mk*16+quad*4+r
            f32x4 sacc[4][2];
#pragma unroll
            for (int mk = 0; mk < 4; mk++)
#pragma unroll
                for (int nq = 0; nq < 2; nq++) sacc[mk][nq] = (f32x4)0.0f;
#pragma unroll
            for (int mk = 0; mk < 4; mk++)
#pragma unroll
                for (int ks = 0; ks < 4; ks++) {
                    short8 kf = *(const short8*)(&Kl[mk * 16 + l15][ks * 32 + quad * 8]);
#pragma unroll
                    for (int nq = 0; nq < 2; nq++)
                        sacc[mk][nq] = __builtin_amdgcn_mfma_f32_16x16x32_bf16(
                            kf, qf[nq][ks], sacc[mk][nq], 0, 0, 0);
                }

            // per-lane softmax + packed b64 P writes
#pragma unroll
            for (int nq = 0; nq < 2; nq++) {
                const int qg = base + nq * 16 + l15;      // this lane's q row
#pragma unroll
                for (int mk = 0; mk < 4; mk++) {
                    float e0, e1, e2, e3;
                    if (j0 + mk * 16 + 15 > base + nq * 16) {   // uniform branch
                        int kv = j0 + mk * 16 + quad * 4;
                        e0 = (kv + 0 > qg) ? 0.0f : __expf(sacc[mk][nq][0]);
                        e1 = (kv + 1 > qg) ? 0.0f : __expf(sacc[mk][nq][1]);
                        e2 = (kv + 2 > qg) ? 0.0f : __expf(sacc[mk][nq][2]);
                        e3 = (kv + 3 > qg) ? 0.0f : __expf(sacc[mk][nq][3]);
                    } else {
                        e0 = __expf(sacc[mk][nq][0]);
                        e1 = __expf(sacc[mk][nq][1]);
                        e2 = __expf(sacc[mk][nq][2]);
                        e3 = __expf(sacc[mk][nq][3]);
                    }
                    l_vec[nq] += (e0 + e1) + (e2 + e3);
                    ushort4 pk;
                    pk.x = f2bf(e0); pk.y = f2bf(e1);
                    pk.z = f2bf(e2); pk.w = f2bf(e3);
                    *(ushort4*)(&Pl[wave][nq * 16 + l15][mk * 16 + quad * 4]) = pk;
                }
            }

            // O += P V  (A=pf [q][kv] b128, B=vf from Vt [d][kv] b128)
#pragma unroll
            for (int ks = 0; ks < 2; ks++) {
                short8 pf[2];
#pragma unroll
                for (int oq = 0; oq < 2; oq++)
                    pf[oq] = *(const short8*)(&Pl[wave][oq * 16 + l15][ks * 32 + quad * 8]);
#pragma unroll
                for (int df = 0; df < 8; df++) {
                    short8 vf = *(const short8*)(&Vt[df * 16 + l15][ks * 32 + quad * 8]);
#pragma unroll
                    for (int oq = 0; oq < 2; oq++)
                        o[oq][df] = __builtin_amdgcn_mfma_f32_16x16x32_bf16(
                            pf[oq], vf, o[oq][df], 0, 0, 0);
                }
            }
        }

        // reduce l across quads (kv-chunks): every lane then holds l for
        // q = base + nq*16 + l15
        float l_full[2];
#pragma unroll
        for (int nq = 0; nq < 2; nq++) {
            float l = l_vec[nq];
            l += __shfl_xor(l, 16);
            l += __shfl_xor(l, 32);
            l_full[nq] = l;
        }

        if (seg_part[s]) {
#pragma unroll
            for (int nq = 0; nq < 2; nq++)
                if (quad == 0)
                    atomicAdd(&l_slot[slot * 128 + wave * 32 + nq * 16 + l15], l_full[nq]);
#pragma unroll
            for (int oq = 0; oq < 2; oq++)
#pragma unroll
                for (int r = 0; r < 4; r++) {
                    int row_l = wave * 32 + oq * 16 + quad * 4 + r;   // 0..127
#pragma unroll
                    for (int df = 0; df < 8; df++)
                        atomicAdd(&o_slot[((size_t)slot * 128 + row_l) * 128
                                          + df * 16 + l15], o[oq][df][r]);
                }
        } else {
#pragma unroll
            for (int oq = 0; oq < 2; oq++)
#pragma unroll
                for (int r = 0; r < 4; r++) {
                    float lq = __shfl(l_full[oq], quad * 4 + r);  // l for this o-row
                    float inv = 1.0f / lq;
                    int row = base + oq * 16 + quad * 4 + r;
#pragma unroll
                    for (int df = 0; df < 8; df++) {
                        float v = o[oq][df][r] * inv;
                        out[(size_t)row * (NHEAD * DHEAD) + head * DHEAD
                            + df * 16 + l15] = f2bf(v);
                    }
                }
        }
    }
}

// ---------------------------------------------------------------------------
// Normalize split-strip slots -> attn (bf16)
// ---------------------------------------------------------------------------
__global__ __launch_bounds__(256)
void fixup_norm(const float* __restrict__ o_slot, const float* __restrict__ l_slot,
                ushort* __restrict__ attn)
{
    const int slot = blockIdx.x;          // 0..255
    const int head = slot >> 4;
    const int pair = slot & 15;
    const int q0   = (31 - pair) * 128;
    const int t    = threadIdx.x;
#pragma unroll 4
    for (int i = 0; i < 64; i++) {
        int idx = i * 256 + t;            // 0..16383
        int row = idx >> 7, d = idx & 127;
        float l = l_slot[slot * 128 + row];
        float v = o_slot[(size_t)slot * 16384 + idx] / l;
        attn[(size_t)(q0 + row) * HID_DIM + head * DHEAD + d] = f2bf(v);
    }
}

// ---------------------------------------------------------------------------
extern "C" void kernel_launch(void* const* d_in, const int* in_sizes, int n_in,
                              void* d_out, int out_size, void* d_ws, size_t ws_size,
                              hipStream_t stream)
{
    const float* x     = (const float*)d_in[0];
    const float* wqkv  = (const float*)d_in[1];
    const float* wproj = (const float*)d_in[2];
    float* outp = (float*)d_out;

    const size_t n_x     = (size_t)S_LEN * HID_DIM;     // 8,388,608
    const size_t n_wqkv  = (size_t)TOTAL * HID_DIM;     // 6,291,456
    const size_t n_wproj = (size_t)HID_DIM * HID_DIM;   // 4,194,304
    const size_t n_qkv   = (size_t)S_LEN * TOTAL;
    const size_t n_attn  = (size_t)S_LEN * HID_DIM;

    ushort* xb     = (ushort*)d_ws;                     // dead after GEMM1
    ushort* wqkvb  = xb + n_x;                          // dead after GEMM1
    ushort* qkv    = wqkvb + n_wqkv;
    ushort* attn   = qkv + n_qkv;
    ushort* vt     = attn + n_attn;                     // [4][128][4096]
    float* o_slot  = (float*)xb;                        // 256*16384 f32 (exact fit)
    float* l_slot  = (float*)wqkvb;                     // 256*128 f32
    ushort* wprojb = wqkvb;                             // converted after flash

    cvt_f32_bf16<<<2048, 256, 0, stream>>>(x, xb, (int)(n_x / 4), 0);
    cvt_f32_bf16<<<2048, 256, 0, stream>>>(wqkv, wqkvb, (int)(n_wqkv / 4), 1);

    // 1) qkv = x @ wqkv^T (+ V^T side-write; V region not stored to qkv)
    gemm_bt<ushort, true><<<dim3(TOTAL / 128, S_LEN / 128), 256, 0, stream>>>(
        xb, wqkvb, qkv, vt, S_LEN, TOTAL, HID_DIM);

    // zero the partial-accumulation slots (xb/wqkvb now dead)
    zero_f4<<<1024, 256, 0, stream>>>((float4*)o_slot, 256 * 16384 / 4);
    zero_f4<<<64, 256, 0, stream>>>((float4*)l_slot, 256 * 128 / 4);

    // 2) attention (512 identical-work blocks, split strips via atomics)
    flash_attn<<<512, 256, 0, stream>>>(qkv, vt, attn, o_slot, l_slot);
    fixup_norm<<<256, 256, 0, stream>>>(o_slot, l_slot, attn);

    // 3) convert wproj (into dead wqkvb region), then out = attn @ wproj^T
    cvt_f32_bf16<<<2048, 256, 0, stream>>>(wproj, wprojb, (int)(n_wproj / 4), 0);
    gemm_bt<float, false><<<dim3(HID_DIM / 128, S_LEN / 128), 256, 0, stream>>>(
        attn, wprojb, outp, nullptr, S_LEN, HID_DIM, HID_DIM);
}

// Round 9
// 425.265 us; speedup vs baseline: 1.0122x; 1.0122x over previous
//
#include <hip/hip_runtime.h>
#include <hip/hip_bf16.h>
#include <stdint.h>

typedef __attribute__((ext_vector_type(8))) short short8;
typedef __attribute__((ext_vector_type(4))) float f32x4;

#define S_LEN   4096
#define HID_DIM 2048
#define NHEAD   16
#define NKV     4
#define DHEAD   128
#define QPG     4
#define GROUP   768   // (QPG+2)*DHEAD
#define TOTAL   3072  // NKV*GROUP

// v_exp_f32 computes 2^x natively
#define EXP2F(x) __builtin_amdgcn_exp2f(x)

__device__ __forceinline__ ushort f2bf(float f) {
    union { float f; uint32_t u; } c; c.f = f;
    uint32_t u = c.u;
    u += 0x7fff + ((u >> 16) & 1);   // RNE
    return (ushort)(u >> 16);
}
__device__ __forceinline__ float bf2f(ushort u) {
    union { uint32_t u; float f; } c; c.u = ((uint32_t)u) << 16;
    return c.f;
}

__device__ __forceinline__ void gld_lds16(const void* g, void* l) {
    __builtin_amdgcn_global_load_lds(
        (const __attribute__((address_space(1))) void*)g,
        (__attribute__((address_space(3))) void*)l, 16, 0, 0);
}

// ---------------------------------------------------------------------------
// fp32 -> bf16 convert. mode 1: scale q-head rows of wqkv by log2(e)/sqrt(D)
// (softmax computed with exp2)
// ---------------------------------------------------------------------------
__global__ __launch_bounds__(256)
void cvt_f32_bf16(const float* __restrict__ src, ushort* __restrict__ dst,
                  int n4, int mode)
{
    int i = blockIdx.x * blockDim.x + threadIdx.x;
    int stride = gridDim.x * blockDim.x;
    for (; i < n4; i += stride) {
        float sc = 1.0f;
        if (mode == 1) {
            int row = i >> 9;                      // (i*4)/2048
            sc = ((row % GROUP) < QPG * DHEAD) ? 0.12751744157413583f : 1.0f;
        }
        float4 v = ((const float4*)src)[i];
        ushort4 o;
        o.x = f2bf(v.x * sc); o.y = f2bf(v.y * sc);
        o.z = f2bf(v.z * sc); o.w = f2bf(v.w * sc);
        ((ushort4*)dst)[i] = o;
    }
}

// ---------------------------------------------------------------------------
// C[M,N] = A[M,K] * B[N,K]^T (bf16 in, fp32 accum). m97-style staging.
// Tile: 128 x (32*NJ). NJ=6 -> 192-wide (GEMM1, 512 tiles exact); NJ=4 -> 128.
// WRITE_VT: fragments in V column range ((col%768)>=640) go transposed to VT.
// ---------------------------------------------------------------------------
__device__ __forceinline__ void store_c(ushort* C, size_t idx, float v) { C[idx] = f2bf(v); }
__device__ __forceinline__ void store_c(float*  C, size_t idx, float v) { C[idx] = v; }

template <typename OutT, int NJ, bool WRITE_VT>
__global__ __launch_bounds__(256, 2)
void gemm_bt(const ushort* __restrict__ A, const ushort* __restrict__ B,
             OutT* __restrict__ C, ushort* __restrict__ VT,
             int M, int N, int K)
{
    __shared__ alignas(16) ushort Asl[128 * 32];
    __shared__ alignas(16) ushort Bsl[NJ * 32 * 32];

    const int tid  = threadIdx.x;
    const int wave = tid >> 6;
    const int lane = tid & 63;
    const int quad = lane >> 4;
    const int l15  = lane & 15;
    const int wr   = wave >> 1;
    const int wc   = wave & 1;
    const int m0   = blockIdx.y * 128;
    const int n0   = blockIdx.x * (32 * NJ);

    f32x4 acc[4][NJ];
#pragma unroll
    for (int i = 0; i < 4; i++)
#pragma unroll
        for (int j = 0; j < NJ; j++) acc[i][j] = (f32x4)0.0f;

    for (int kb = 0; kb < K; kb += 32) {
        __syncthreads();
        // A: 512 chunks of 16B; B: 128*NJ chunks. 2 + NJ/2 iters of 256.
#pragma unroll
        for (int k = 0; k < 2 + NJ / 2; k++) {
            int idx = k * 256 + tid;
            if (idx < 512) {
                const ushort* g = A + (size_t)(m0 + (idx >> 2)) * K + kb + (idx & 3) * 8;
                gld_lds16(g, (char*)Asl + (size_t)(k * 256 + wave * 64) * 16);
            } else {
                int j = idx - 512;
                const ushort* g = B + (size_t)(n0 + (j >> 2)) * K + kb + (j & 3) * 8;
                gld_lds16(g, (char*)Bsl + (size_t)((k - 2) * 256 + wave * 64) * 16);
            }
        }
        __syncthreads();   // drains vmcnt -> LDS valid

        short8 af[4], bf[NJ];
#pragma unroll
        for (int i = 0; i < 4; i++)
            af[i] = *(const short8*)(&Asl[(wr * 64 + i * 16 + l15) * 32 + quad * 8]);
#pragma unroll
        for (int j = 0; j < NJ; j++)
            bf[j] = *(const short8*)(&Bsl[(wc * 16 * NJ + j * 16 + l15) * 32 + quad * 8]);
#pragma unroll
        for (int i = 0; i < 4; i++)
#pragma unroll
            for (int j = 0; j < NJ; j++)
                acc[i][j] = __builtin_amdgcn_mfma_f32_16x16x32_bf16(
                    af[i], bf[j], acc[i][j], 0, 0, 0);
    }

    // epilogue: C/D layout col=lane&15, row=quad*4+reg
#pragma unroll
    for (int j = 0; j < NJ; j++) {
        const int colb = n0 + wc * 16 * NJ + j * 16;   // fragment base column
        const int cgrp = colb % GROUP;
        if (WRITE_VT && cgrp >= (QPG + 1) * DHEAD) {
            // V fragment -> transposed VT[g][d][s] (not stored to qkv)
            const int g = colb / GROUP;
            const int d = cgrp - (QPG + 1) * DHEAD + l15;
#pragma unroll
            for (int i = 0; i < 4; i++) {
                int row0 = m0 + wr * 64 + i * 16 + quad * 4;
                ushort4 pk;
                pk.x = f2bf(acc[i][j][0]); pk.y = f2bf(acc[i][j][1]);
                pk.z = f2bf(acc[i][j][2]); pk.w = f2bf(acc[i][j][3]);
                *(ushort4*)(VT + (size_t)(g * 128 + d) * S_LEN + row0) = pk;
            }
        } else {
#pragma unroll
            for (int i = 0; i < 4; i++)
#pragma unroll
                for (int r = 0; r < 4; r++) {
                    int row = m0 + wr * 64 + i * 16 + quad * 4 + r;
                    store_c(C, (size_t)row * N + colb + l15, acc[i][j][r]);
                }
        }
    }
}

// ---------------------------------------------------------------------------
// Causal GQA flash attention, exactly-balanced (split heavy strips, 33 units
// per block). S^T = K*Q^T so softmax is per-lane; exp2-based (Q pre-scaled by
// log2e/sqrt(D)). Partial halves store bf16 o / f32 l to disjoint regions
// (NO atomics); light strips normalize inline.
// ---------------------------------------------------------------------------
__global__ __launch_bounds__(256, 2)
void flash_attn(const ushort* __restrict__ qkv, const ushort* __restrict__ VT,
                ushort* __restrict__ out, ushort* __restrict__ o_part,
                float* __restrict__ l_part)
{
    const int b    = blockIdx.x;
    const int head = b >> 5;
    const int pair = (b >> 1) & 15;
    const int half = b & 1;
    const int g    = head >> 2;
    const int qh   = head & 3;
    const int p_h  = 31 - pair;
    const int H    = 2 * p_h + 2;           // 34..64
    const int hslot = (head * 16 + pair) * 2 + half;

    const int tid  = threadIdx.x;
    const int wave = tid >> 6;
    const int lane = tid & 63;
    const int quad = lane >> 4;
    const int l15  = lane & 15;

    __shared__ alignas(16) ushort Kl[64][136];    // [kv][d]
    __shared__ alignas(16) ushort Vt[128][72];    // [d][kv]
    __shared__ alignas(16) ushort Pl[4][32][66];  // per-wave P [q][kv]

    int seg_p[2], seg_t0[2], seg_t1[2], seg_part[2];
    int nseg;
    if (half == 0) {
        nseg = 1;
        seg_p[0] = p_h;  seg_t0[0] = 0;  seg_t1[0] = 33;           seg_part[0] = 1;
    } else {
        nseg = 2;
        seg_p[0] = p_h;  seg_t0[0] = 33; seg_t1[0] = H;            seg_part[0] = 1;
        seg_p[1] = pair; seg_t0[1] = 0;  seg_t1[1] = 2 * pair + 2; seg_part[1] = 0;
    }

    const int koff = g * GROUP + QPG * DHEAD;

    for (int s = 0; s < nseg; s++) {
        const int p  = seg_p[s];
        const int t0 = seg_t0[s];
        const int t1 = seg_t1[s];
        const int q0 = p * 128;
        const int base = q0 + wave * 32;

        // Q fragments (B-operand layout)
        short8 qf[2][4];
#pragma unroll
        for (int nq = 0; nq < 2; nq++) {
            int row = base + nq * 16 + l15;
            const ushort* qp = qkv + (size_t)row * TOTAL + g * GROUP + qh * DHEAD + quad * 8;
#pragma unroll
            for (int ks = 0; ks < 4; ks++)
                qf[nq][ks] = *(const short8*)(qp + ks * 32);
        }

        f32x4 o[2][8];
#pragma unroll
        for (int oq = 0; oq < 2; oq++)
#pragma unroll
            for (int df = 0; df < 8; df++) o[oq][df] = (f32x4)0.0f;
        float l_vec[2] = {0.0f, 0.0f};

        float4 kpre[4], vpre[4];
#pragma unroll
        for (int r = 0; r < 4; r++) {
            int c = tid + r * 256;
            int kr = c >> 4, kc = c & 15;
            kpre[r] = *(const float4*)(qkv + (size_t)(t0 * 64 + kr) * TOTAL + koff + kc * 8);
            int vd = c >> 3, vc = c & 7;
            vpre[r] = *(const float4*)(VT + (size_t)(g * 128 + vd) * S_LEN + t0 * 64 + vc * 8);
        }

        for (int t = t0; t < t1; t++) {
            __syncthreads();
#pragma unroll
            for (int r = 0; r < 4; r++) {
                int c = tid + r * 256;
                int kr = c >> 4, kc = c & 15;
                *(float4*)(&Kl[kr][kc * 8]) = kpre[r];
                int vd = c >> 3, vc = c & 7;
                *(float4*)(&Vt[vd][vc * 8]) = vpre[r];
            }
            __syncthreads();

            if (t + 1 < t1) {
                const int j1 = (t + 1) * 64;
#pragma unroll
                for (int r = 0; r < 4; r++) {
                    int c = tid + r * 256;
                    int kr = c >> 4, kc = c & 15;
                    kpre[r] = *(const float4*)(qkv + (size_t)(j1 + kr) * TOTAL + koff + kc * 8);
                    int vd = c >> 3, vc = c & 7;
                    vpre[r] = *(const float4*)(VT + (size_t)(g * 128 + vd) * S_LEN + j1 + vc * 8);
                }
            }

            const int j0 = t * 64;
            // S^T = K * Q^T
            f32x4 sacc[4][2];
#pragma unroll
            for (int mk = 0; mk < 4; mk++)
#pragma unroll
                for (int nq = 0; nq < 2; nq++) sacc[mk][nq] = (f32x4)0.0f;
#pragma unroll
            for (int mk = 0; mk < 4; mk++)
#pragma unroll
                for (int ks = 0; ks < 4; ks++) {
                    short8 kf = *(const short8*)(&Kl[mk * 16 + l15][ks * 32 + quad * 8]);
#pragma unroll
                    for (int nq = 0; nq < 2; nq++)
                        sacc[mk][nq] = __builtin_amdgcn_mfma_f32_16x16x32_bf16(
                            kf, qf[nq][ks], sacc[mk][nq], 0, 0, 0);
                }

            // per-lane exp2 softmax + packed b64 P writes
#pragma unroll
            for (int nq = 0; nq < 2; nq++) {
                const int qg = base + nq * 16 + l15;
#pragma unroll
                for (int mk = 0; mk < 4; mk++) {
                    float e0, e1, e2, e3;
                    if (j0 + mk * 16 + 15 > base + nq * 16) {   // uniform branch
                        int kv = j0 + mk * 16 + quad * 4;
                        e0 = (kv + 0 > qg) ? 0.0f : EXP2F(sacc[mk][nq][0]);
                        e1 = (kv + 1 > qg) ? 0.0f : EXP2F(sacc[mk][nq][1]);
                        e2 = (kv + 2 > qg) ? 0.0f : EXP2F(sacc[mk][nq][2]);
                        e3 = (kv + 3 > qg) ? 0.0f : EXP2F(sacc[mk][nq][3]);
                    } else {
                        e0 = EXP2F(sacc[mk][nq][0]);
                        e1 = EXP2F(sacc[mk][nq][1]);
                        e2 = EXP2F(sacc[mk][nq][2]);
                        e3 = EXP2F(sacc[mk][nq][3]);
                    }
                    l_vec[nq] += (e0 + e1) + (e2 + e3);
                    ushort4 pk;
                    pk.x = f2bf(e0); pk.y = f2bf(e1);
                    pk.z = f2bf(e2); pk.w = f2bf(e3);
                    *(ushort4*)(&Pl[wave][nq * 16 + l15][mk * 16 + quad * 4]) = pk;
                }
            }

            // O += P V
#pragma unroll
            for (int ks = 0; ks < 2; ks++) {
                short8 pf[2];
#pragma unroll
                for (int oq = 0; oq < 2; oq++)
                    pf[oq] = *(const short8*)(&Pl[wave][oq * 16 + l15][ks * 32 + quad * 8]);
#pragma unroll
                for (int df = 0; df < 8; df++) {
                    short8 vf = *(const short8*)(&Vt[df * 16 + l15][ks * 32 + quad * 8]);
#pragma unroll
                    for (int oq = 0; oq < 2; oq++)
                        o[oq][df] = __builtin_amdgcn_mfma_f32_16x16x32_bf16(
                            pf[oq], vf, o[oq][df], 0, 0, 0);
                }
            }
        }

        // l reduce across quads (kv-chunks)
        float l_full[2];
#pragma unroll
        for (int nq = 0; nq < 2; nq++) {
            float l = l_vec[nq];
            l += __shfl_xor(l, 16);
            l += __shfl_xor(l, 32);
            l_full[nq] = l;
        }

        if (seg_part[s]) {
            // deterministic partial store (bf16 o, f32 l), region private to hslot
            ushort* po = o_part + (size_t)hslot * 16384;
#pragma unroll
            for (int nq = 0; nq < 2; nq++)
                if (quad == 0)
                    l_part[hslot * 128 + wave * 32 + nq * 16 + l15] = l_full[nq];
#pragma unroll
            for (int oq = 0; oq < 2; oq++)
#pragma unroll
                for (int r = 0; r < 4; r++) {
                    int row_l = wave * 32 + oq * 16 + quad * 4 + r;
#pragma unroll
                    for (int df = 0; df < 8; df++)
                        po[row_l * 128 + df * 16 + l15] = f2bf(o[oq][df][r]);
                }
        } else {
#pragma unroll
            for (int oq = 0; oq < 2; oq++)
#pragma unroll
                for (int r = 0; r < 4; r++) {
                    float lq = __shfl(l_full[oq], quad * 4 + r);
                    float inv = 1.0f / lq;
                    int row = base + oq * 16 + quad * 4 + r;
#pragma unroll
                    for (int df = 0; df < 8; df++) {
                        float v = o[oq][df][r] * inv;
                        out[(size_t)row * (NHEAD * DHEAD) + head * DHEAD
                            + df * 16 + l15] = f2bf(v);
                    }
                }
        }
    }
}

// ---------------------------------------------------------------------------
// Sum the two half partials, normalize -> attn (bf16)
// ---------------------------------------------------------------------------
__global__ __launch_bounds__(256)
void fixup_norm(const ushort* __restrict__ o_part, const float* __restrict__ l_part,
                ushort* __restrict__ attn)
{
    const int slot = blockIdx.x;          // 0..255
    const int head = slot >> 4;
    const int pair = slot & 15;
    const int q0   = (31 - pair) * 128;
    const int t    = threadIdx.x;
    const ushort* p0 = o_part + (size_t)(slot * 2) * 16384;
    const ushort* p1 = p0 + 16384;
#pragma unroll 4
    for (int i = 0; i < 64; i++) {
        int idx = i * 256 + t;            // 0..16383
        int row = idx >> 7, d = idx & 127;
        float l = l_part[(slot * 2) * 128 + row] + l_part[(slot * 2 + 1) * 128 + row];
        float v = (bf2f(p0[idx]) + bf2f(p1[idx])) / l;
        attn[(size_t)(q0 + row) * HID_DIM + head * DHEAD + d] = f2bf(v);
    }
}

// ---------------------------------------------------------------------------
extern "C" void kernel_launch(void* const* d_in, const int* in_sizes, int n_in,
                              void* d_out, int out_size, void* d_ws, size_t ws_size,
                              hipStream_t stream)
{
    const float* x     = (const float*)d_in[0];
    const float* wqkv  = (const float*)d_in[1];
    const float* wproj = (const float*)d_in[2];
    float* outp = (float*)d_out;

    const size_t n_x     = (size_t)S_LEN * HID_DIM;     // 8,388,608
    const size_t n_wqkv  = (size_t)TOTAL * HID_DIM;     // 6,291,456
    const size_t n_wproj = (size_t)HID_DIM * HID_DIM;   // 4,194,304
    const size_t n_qkv   = (size_t)S_LEN * TOTAL;
    const size_t n_attn  = (size_t)S_LEN * HID_DIM;

    ushort* xb     = (ushort*)d_ws;                     // dead after GEMM1
    ushort* wqkvb  = xb + n_x;                          // dead after GEMM1
    ushort* qkv    = wqkvb + n_wqkv;
    ushort* attn   = qkv + n_qkv;
    ushort* vt     = attn + n_attn;                     // [4][128][4096]
    ushort* o_part = xb;                                // 512*16384 bf16 (exact fit)
    float*  l_part = (float*)wqkvb;                     // 512*128 f32
    ushort* wprojb = wqkvb;                             // reused after fixup

    cvt_f32_bf16<<<2048, 256, 0, stream>>>(x, xb, (int)(n_x / 4), 0);
    cvt_f32_bf16<<<2048, 256, 0, stream>>>(wqkv, wqkvb, (int)(n_wqkv / 4), 1);

    // 1) qkv = x @ wqkv^T (+ V^T side-write). 192-wide tiles: 16x32 = 512 blocks.
    gemm_bt<ushort, 6, true><<<dim3(TOTAL / 192, S_LEN / 128), 256, 0, stream>>>(
        xb, wqkvb, qkv, vt, S_LEN, TOTAL, HID_DIM);

    // 2) attention (512 identical-work blocks; deterministic partial regions)
    flash_attn<<<512, 256, 0, stream>>>(qkv, vt, attn, o_part, l_part);
    fixup_norm<<<256, 256, 0, stream>>>(o_part, l_part, attn);

    // 3) convert wproj (into dead wqkvb region), then out = attn @ wproj^T
    cvt_f32_bf16<<<2048, 256, 0, stream>>>(wproj, wprojb, (int)(n_wproj / 4), 0);
    gemm_bt<float, 4, false><<<dim3(HID_DIM / 128, S_LEN / 128), 256, 0, stream>>>(
        attn, wprojb, outp, nullptr, S_LEN, HID_DIM, HID_DIM);
}